// Round 21
// baseline (41.638 us; speedup 1.0000x reference)
//
#include <hip/hip_runtime.h>
#include <hip/hip_fp16.h>

typedef __attribute__((ext_vector_type(4))) float f32x4;
typedef __attribute__((ext_vector_type(4))) int i32x4;
typedef __attribute__((ext_vector_type(8))) int i32x8;

#define NROWS 8192
#define DCOLS 256
#define MARGIN 0.5f
#define NCT 64         // 128-col tiles
#define NBLOCKS 1088   // sum over 128 bands of ceil((64 - band/2)/4)

// --- Kernel 1: L2-normalize rows fp32 -> fp8 e5m2 (= truncated fp16), row-major.
__global__ __launch_bounds__(256) void norm_kernel(const float* __restrict__ x,
                                                   unsigned char* __restrict__ e) {
    const int t = threadIdx.x;
    const int l = t & 63;
    const int c = l & 31;
    const int row = blockIdx.x * 8 + (t >> 6) * 2 + (l >> 5);

    const float4 v0 = *reinterpret_cast<const float4*>(&x[row * DCOLS + c * 8]);
    const float4 v1 = *reinterpret_cast<const float4*>(&x[row * DCOLS + c * 8 + 4]);
    float ss = v0.x * v0.x + v0.y * v0.y + v0.z * v0.z + v0.w * v0.w
             + v1.x * v1.x + v1.y * v1.y + v1.z * v1.z + v1.w * v1.w;
#pragma unroll
    for (int off = 16; off >= 1; off >>= 1) ss += __shfl_xor(ss, off, 32);
    const float inv = 1.0f / fmaxf(sqrtf(ss), 1e-12f);

    const float f[8] = {v0.x, v0.y, v0.z, v0.w, v1.x, v1.y, v1.z, v1.w};
    unsigned int lo = 0, hi = 0;
#pragma unroll
    for (int i = 0; i < 4; ++i) {
        const unsigned short hb = __half_as_ushort(__float2half(f[i] * inv));
        lo |= (unsigned int)(hb >> 8) << (8 * i);           // e5m2 = fp16 top byte
    }
#pragma unroll
    for (int i = 0; i < 4; ++i) {
        const unsigned short hb = __half_as_ushort(__float2half(f[4 + i] * inv));
        hi |= (unsigned int)(hb >> 8) << (8 * i);
    }
    uint2 o; o.x = lo; o.y = hi;
    *reinterpret_cast<uint2*>(e + (size_t)row * DCOLS + c * 8) = o;
}

// --- Kernel 2: R21 = intensity (A-reuse runs) + counted gates + 4 waves/SIMD.
// Block = (band bi of 64 rows, run of <=4 col-tiles of 128). 512 thr = 8 waves
// (2M x 4N), wave tile 32x32: acc[2][2] of mfma_scale_f32_16x16x128 (bf8/bf8,
// scale=1.0; call verified in-context R18). ~95 VGPR @ (512,4) -> 4 waves/SIMD;
// LDS 64KB (A 16KB full-K + block-shared B ring-3 x 16KB) -> 2 blocks/CU.
// Per step: {vmcnt(2); s_barrier; stage B(s+2) -> slot read at step s-1 (the
// barrier orders those reads: no lgkmcnt pin); 8x ds_read_b128; 4 MFMA}.
// Layouts: split-half k-major, lanes stride-16B per 16-lane phase (R13-verified
// conflict-free); linear LDS dest + permuted global source (rule #21).
__global__ __launch_bounds__(512, 4) void tile_kernel(const unsigned char* __restrict__ e,
                                                      float* __restrict__ part) {
    // XCD swizzle (1088 = 8*136), then band/run decode
    const int orig = blockIdx.x;
    int bb = (orig & 7) * 136 + (orig >> 3);
    int bi = 0, r;
    while (bb >= (r = ((NCT - (bi >> 1)) + 3) >> 2)) { bb -= r; ++bi; }
    const int j0 = (bi >> 1) + bb * 4;        // first col-tile of run
    const int nj = min(4, NCT - j0);
    const int NS = nj * 2;                    // (tile, kb) streams

    __shared__ char As[16384];                // [kb][half][hk][arow 0..63][16B]
    __shared__ char Bs[3][16384];             // slot: [half][hk][brow 0..127][16B]
    __shared__ float red[8];

    const int t = threadIdx.x;
    const int l = t & 63;
    const int w = t >> 6;        // 0..7
    const int wm = w >> 2;       // 0..1: rows wm*32
    const int wn = w & 3;        // 0..3: cols wn*32
    const int lr = l & 15;
    const int hk = l >> 4;

    const unsigned char* eA = e + (size_t)bi * 64 * DCOLS;

    // stage B stream s (tile j0+(s>>1), kb=s&1): 16KB, 2 chunks/thread.
    auto stageB = [&](int s, int slot) {
        const int jt = j0 + (s >> 1), kb = s & 1;
#pragma unroll
        for (int i = 0; i < 2; ++i) {
            const int u = i * 512 + t;        // 0..1023
            const int half = u >> 9, shk = (u >> 7) & 3, brow = u & 127;
            __builtin_amdgcn_global_load_lds(
                (const __attribute__((address_space(1))) void*)(e
                    + (size_t)(jt * 128 + brow) * DCOLS + kb * 128 + shk * 32 + half * 16),
                (__attribute__((address_space(3))) void*)(Bs[slot] + u * 16), 16, 0, 0);
        }
    };

    // --- prologue: A full-K (2 chunks/thread) + B streams 0,1 -> slots 0,1 ---
#pragma unroll
    for (int i = 0; i < 2; ++i) {
        const int u = i * 512 + t;            // 0..1023
        const int kb = u >> 9, half = (u >> 8) & 1, shk = (u >> 6) & 3, arow = u & 63;
        __builtin_amdgcn_global_load_lds(
            (const __attribute__((address_space(1))) void*)(eA + arow * DCOLS + kb * 128 + shk * 32 + half * 16),
            (__attribute__((address_space(3))) void*)(As + u * 16), 16, 0, 0);
    }
    stageB(0, 0);
    stageB(1, 1);

    f32x4 acc[2][2];
#pragma unroll
    for (int m = 0; m < 2; ++m)
#pragma unroll
        for (int n = 0; n < 2; ++n)
            acc[m][n] = (f32x4){0.f, 0.f, 0.f, 0.f};

    // lane read bases (conflict-free: 16-lane phases stride 16B)
    const int abase = hk * 1024 + (wm * 32 + lr) * 16;   // + m*256 + kb*8192; hi +4096
    const int bbase = hk * 2048 + (wn * 32 + lr) * 16;   // + n*256; hi +8192

    float local = 0.0f;
    int sl = 0;                                // s % 3
    for (int jx = 0; jx < nj; ++jx) {
        const int jt = j0 + jx;
#pragma unroll
        for (int kb = 0; kb < 2; ++kb) {
            const int s = jx * 2 + kb;
            // counted gate: stage(s) landed (stage(s+1)'s 2 loads stay in flight)
            asm volatile("s_waitcnt vmcnt(2)" ::: "memory");
            __builtin_amdgcn_s_barrier();      // publishes stream s (and A at s=0)
            // stage s+2 into slot (sl+2)%3 = slot last read at step s-1
            // (those reads completed before this barrier -> safe, no lgkm pin)
            if (s + 2 < NS) {
                int sl2 = sl + 2; if (sl2 >= 3) sl2 -= 3;
                stageB(s + 2, sl2);
            }
            i32x8 af[2], bf[2];
#pragma unroll
            for (int m = 0; m < 2; ++m) {
                i32x4 lo = *reinterpret_cast<const i32x4*>(As + kb * 8192 + m * 256 + abase);
                i32x4 hi = *reinterpret_cast<const i32x4*>(As + kb * 8192 + 4096 + m * 256 + abase);
                af[m] = (i32x8){lo[0], lo[1], lo[2], lo[3], hi[0], hi[1], hi[2], hi[3]};
            }
#pragma unroll
            for (int n = 0; n < 2; ++n) {
                i32x4 lo = *reinterpret_cast<const i32x4*>(Bs[sl] + n * 256 + bbase);
                i32x4 hi = *reinterpret_cast<const i32x4*>(Bs[sl] + 8192 + n * 256 + bbase);
                bf[n] = (i32x8){lo[0], lo[1], lo[2], lo[3], hi[0], hi[1], hi[2], hi[3]};
            }
            __builtin_amdgcn_s_setprio(1);
#pragma unroll
            for (int m = 0; m < 2; ++m)
#pragma unroll
                for (int n = 0; n < 2; ++n)
                    acc[m][n] = __builtin_amdgcn_mfma_scale_f32_16x16x128_f8f6f4(
                        af[m], bf[n], acc[m][n],
                        1, 1,                 // cbsz=BF8(e5m2), blgp=BF8
                        0, 0x7F7F7F7F,        // scale A = 1.0
                        0, 0x7F7F7F7F);       // scale B = 1.0
            __builtin_amdgcn_s_setprio(0);
            ++sl; if (sl >= 3) sl -= 3;
        }
        // --- tile jt complete: fused masked-relu reduce, reset acc ---
        // C/D layout (m89-verified; shape-determined): col=lane&15,
        // row=(lane>>4)*4+reg.
        const int gi0 = bi * 64 + wm * 32;
        const int gj0 = jt * 128 + wn * 32;
        if (jt == (bi >> 1)) {                // diagonal-crossing tile: mask
#pragma unroll
            for (int m = 0; m < 2; ++m)
#pragma unroll
                for (int n = 0; n < 2; ++n) {
#pragma unroll
                    for (int r2 = 0; r2 < 4; ++r2) {
                        const int gi = gi0 + m * 16 + hk * 4 + r2;
                        const int gj = gj0 + n * 16 + lr;
                        local += (gi < gj) ? fmaxf(acc[m][n][r2] - MARGIN, 0.0f) : 0.0f;
                    }
                    acc[m][n] = (f32x4){0.f, 0.f, 0.f, 0.f};
                }
        } else {                              // jt > bi/2: fully upper-tri
#pragma unroll
            for (int m = 0; m < 2; ++m)
#pragma unroll
                for (int n = 0; n < 2; ++n) {
#pragma unroll
                    for (int r2 = 0; r2 < 4; ++r2)
                        local += fmaxf(acc[m][n][r2] - MARGIN, 0.0f);
                    acc[m][n] = (f32x4){0.f, 0.f, 0.f, 0.f};
                }
        }
    }

    // --- block reduction (8 waves) -> one partial per block, no atomics ---
#pragma unroll
    for (int off = 32; off >= 1; off >>= 1) local += __shfl_down(local, off);
    if (l == 0) red[w] = local;
    __syncthreads();
    if (t == 0) {
        float s = 0.0f;
#pragma unroll
        for (int i = 0; i < 8; ++i) s += red[i];
        part[orig] = s;
    }
}

// --- Kernel 3: reduce NBLOCKS=1088 partials, finalize ---
__global__ __launch_bounds__(256) void fin_kernel(const float* __restrict__ part,
                                                  float* __restrict__ out) {
    __shared__ float red[4];
    const int t = threadIdx.x;
    float v = part[t] + part[t + 256] + part[t + 512] + part[t + 768]
            + (t < NBLOCKS - 1024 ? part[t + 1024] : 0.0f);
#pragma unroll
    for (int off = 32; off >= 1; off >>= 1) v += __shfl_down(v, off);
    if ((t & 63) == 0) red[t >> 6] = v;
    __syncthreads();
    if (t == 0) out[0] = (red[0] + red[1] + red[2] + red[3]) / 33550336.0f;
}

extern "C" void kernel_launch(void* const* d_in, const int* in_sizes, int n_in,
                              void* d_out, int out_size, void* d_ws, size_t ws_size,
                              hipStream_t stream) {
    const float* x = (const float*)d_in[0];
    float* out = (float*)d_out;
    unsigned char* e = (unsigned char*)d_ws;                        // 2 MB fp8
    float* part = (float*)((char*)d_ws + (size_t)NROWS * DCOLS);    // 1088 floats

    norm_kernel<<<NROWS / 8, 256, 0, stream>>>(x, e);
    tile_kernel<<<NBLOCKS, 512, 0, stream>>>(e, part);
    fin_kernel<<<1, 256, 0, stream>>>(part, out);
}

// Round 23
// 38.311 us; speedup vs baseline: 1.0869x; 1.0869x over previous
//
#include <hip/hip_runtime.h>
#include <hip/hip_fp16.h>

typedef __attribute__((ext_vector_type(4))) float f32x4;
typedef __attribute__((ext_vector_type(8))) int i32x8;

#define NROWS 8192
#define DCOLS 256
#define MARGIN 0.5f
#define NT 64          // 8192/128 tiles per dim
#define NBLOCKS 1056   // sum over rows bi of ceil((64-bi)/2), runs of <=2

// --- Kernel 1: L2-normalize rows fp32 -> fp8 e5m2 (= truncated fp16), row-major.
__global__ __launch_bounds__(256) void norm_kernel(const float* __restrict__ x,
                                                   unsigned char* __restrict__ e) {
    const int t = threadIdx.x;
    const int l = t & 63;
    const int c = l & 31;
    const int row = blockIdx.x * 8 + (t >> 6) * 2 + (l >> 5);

    const float4 v0 = *reinterpret_cast<const float4*>(&x[row * DCOLS + c * 8]);
    const float4 v1 = *reinterpret_cast<const float4*>(&x[row * DCOLS + c * 8 + 4]);
    float ss = v0.x * v0.x + v0.y * v0.y + v0.z * v0.z + v0.w * v0.w
             + v1.x * v1.x + v1.y * v1.y + v1.z * v1.z + v1.w * v1.w;
#pragma unroll
    for (int off = 16; off >= 1; off >>= 1) ss += __shfl_xor(ss, off, 32);
    const float inv = 1.0f / fmaxf(sqrtf(ss), 1e-12f);

    const float f[8] = {v0.x, v0.y, v0.z, v0.w, v1.x, v1.y, v1.z, v1.w};
    unsigned int lo = 0, hi = 0;
#pragma unroll
    for (int i = 0; i < 4; ++i) {
        const unsigned short hb = __half_as_ushort(__float2half(f[i] * inv));
        lo |= (unsigned int)(hb >> 8) << (8 * i);           // e5m2 = fp16 top byte
    }
#pragma unroll
    for (int i = 0; i < 4; ++i) {
        const unsigned short hb = __half_as_ushort(__float2half(f[4 + i] * inv));
        hi |= (unsigned int)(hb >> 8) << (8 * i);
    }
    uint2 o; o.x = lo; o.y = hi;
    *reinterpret_cast<uint2*>(e + (size_t)row * DCOLS + c * 8) = o;
}

// --- Kernel 2: R23 = R22 with the stream-1 staging bug fixed (stream 1 =
// (tile j0, kb=1) exists for BOTH nj=1 and nj=2 -> stage unconditionally;
// prologue outstanding is then always 16 and vmcnt(8) retires exactly A).
// Structure (from R18, best 30.8us): 256 thr = 4 free waves, tile 128x128,
// wave owns cols wn*32 -> acc[8][2] of mfma_scale_f32_16x16x128 (bf8/bf8,
// scale=1.0, verified in-context R18). A hoisted to af[2][8] regs via a
// single 32KB LDS round (ONE barrier, no vmcnt(0) drain); B wave-private
// 4KB ring-3, own-vmcnt counted gates, no in-loop barriers. Runs of <=2
// j-tiles (1056 thin blocks) with fully static slots/gates.
__global__ __launch_bounds__(256, 2) void tile_kernel(const unsigned char* __restrict__ e,
                                                      float* __restrict__ part) {
    // XCD swizzle (1056 = 8*132), then row/run decode (runs of <=2)
    const int orig = blockIdx.x;
    int bb = (orig & 7) * 132 + (orig >> 3);
    int bi = 0, r;
    while (bb >= (r = ((NT - bi) + 1) >> 1)) { bb -= r; ++bi; }
    const int j0 = bi + bb * 2;
    const int nj = min(2, NT - j0);

    __shared__ char As[32768];                // [kb 0..1][hk 0..3][row 0..127][32B]
    __shared__ char Bw[4][3][4096];           // [wave][slot][hk 0..3][brow 0..31][32B]
    __shared__ float red[4];

    const int t = threadIdx.x;
    const int l = t & 63;
    const int w = t >> 6;       // wave id: cols wn*32
    const int wn = w;
    const int lr = l & 15;
    const int hk = l >> 4;
    const unsigned char* eA = e + (size_t)bi * 128 * DCOLS;
    char* myB = Bw[w][0];

    // stage one B stream (tile j0+(s>>1), kb = s&1): 4KB, 4 loads/lane.
    auto stageB = [&](int s, int slot) {
        const int jt = j0 + (s >> 1), kb = s & 1;
        const unsigned char* src = e + (size_t)(jt * 128 + wn * 32) * DCOLS + kb * 128;
#pragma unroll
        for (int i = 0; i < 4; ++i) {
            const int u = i * 64 + l;         // 0..255
            const int hk2 = u >> 6, brow = (u >> 1) & 31, half = u & 1;
            __builtin_amdgcn_global_load_lds(
                (const __attribute__((address_space(1))) void*)(src + brow * DCOLS + hk2 * 32 + half * 16),
                (__attribute__((address_space(3))) void*)(myB + slot * 4096 + u * 16), 16, 0, 0);
        }
    };

    // --- prologue (single round): A 32KB (8 loads/thread) + B streams 0,1 ---
#pragma unroll
    for (int i = 0; i < 8; ++i) {
        const int u = i * 256 + t;            // 0..2047
        const int kb = u >> 10, hk2 = (u >> 8) & 3, arow = (u >> 1) & 127, half = u & 1;
        __builtin_amdgcn_global_load_lds(
            (const __attribute__((address_space(1))) void*)(eA + arow * DCOLS + kb * 128 + hk2 * 32 + half * 16),
            (__attribute__((address_space(3))) void*)(As + u * 16), 16, 0, 0);
    }
    stageB(0, 0);                             // stream 0 = (j0, kb0)
    stageB(1, 1);                             // stream 1 = (j0, kb1) — ALWAYS exists
    asm volatile("s_waitcnt vmcnt(8)" ::: "memory");   // 16 outstanding -> A landed
    __builtin_amdgcn_s_barrier();             // the ONLY barrier: publishes A
    __builtin_amdgcn_sched_barrier(0);

    // --- hoist ALL A fragments to registers (one pass; As then dead) ---
    i32x8 af[2][8];
#pragma unroll
    for (int kb = 0; kb < 2; ++kb)
#pragma unroll
        for (int m = 0; m < 8; ++m)
            af[kb][m] = *reinterpret_cast<const i32x8*>(
                As + kb * 16384 + hk * 4096 + (m * 16 + lr) * 32);

    f32x4 acc[8][2];
#pragma unroll
    for (int m = 0; m < 8; ++m)
#pragma unroll
        for (int n = 0; n < 2; ++n)
            acc[m][n] = (f32x4){0.f, 0.f, 0.f, 0.f};

    float local = 0.0f;

    // one (tile, kb) step: gate, optional stage, 2 B-frag reads, 16 MFMA
    auto step = [&](int kb, int slot, int gate, int stage_s, int stage_slot) {
        if (gate == 4) asm volatile("s_waitcnt vmcnt(4)" ::: "memory");
        else           asm volatile("s_waitcnt vmcnt(0)" ::: "memory");
        if (stage_s >= 0) stageB(stage_s, stage_slot);
        i32x8 bf[2];
#pragma unroll
        for (int n = 0; n < 2; ++n)
            bf[n] = *reinterpret_cast<const i32x8*>(
                myB + slot * 4096 + hk * 1024 + (n * 16 + lr) * 32);
        __builtin_amdgcn_s_setprio(1);
#pragma unroll
        for (int m = 0; m < 8; ++m)
#pragma unroll
            for (int n = 0; n < 2; ++n)
                acc[m][n] = __builtin_amdgcn_mfma_scale_f32_16x16x128_f8f6f4(
                    af[kb][m], bf[n], acc[m][n],
                    1, 1,                     // cbsz=BF8(e5m2), blgp=BF8
                    0, 0x7F7F7F7F,            // scale A = 1.0
                    0, 0x7F7F7F7F);           // scale B = 1.0
        __builtin_amdgcn_s_setprio(0);
    };
    // fused masked-relu reduce for completed tile jt; resets acc.
    auto finish_tile = [&](int jt) {
        // C/D layout (m89-verified; shape-determined): col=lane&15,
        // row=(lane>>4)*4+reg.
        const int gi0 = bi * 128;
        const int gj0 = jt * 128 + wn * 32;
        if (jt == bi) {
#pragma unroll
            for (int m = 0; m < 8; ++m)
#pragma unroll
                for (int n = 0; n < 2; ++n) {
#pragma unroll
                    for (int r2 = 0; r2 < 4; ++r2) {
                        const int gi = gi0 + m * 16 + hk * 4 + r2;
                        const int gj = gj0 + n * 16 + lr;
                        local += (gi < gj) ? fmaxf(acc[m][n][r2] - MARGIN, 0.0f) : 0.0f;
                    }
                    acc[m][n] = (f32x4){0.f, 0.f, 0.f, 0.f};
                }
        } else {
#pragma unroll
            for (int m = 0; m < 8; ++m)
#pragma unroll
                for (int n = 0; n < 2; ++n) {
#pragma unroll
                    for (int r2 = 0; r2 < 4; ++r2)
                        local += fmaxf(acc[m][n][r2] - MARGIN, 0.0f);
                    acc[m][n] = (f32x4){0.f, 0.f, 0.f, 0.f};
                }
        }
    };

    // fully static schedule (slots/gates compile-time)
    if (nj == 2) {
        step(0, 0, 4, 2, 2);      // s=0: gate B0 (B1 in flight); stage s2->slot2
        step(1, 1, 4, 3, 0);      // s=1: gate B1; stage s3->slot0 (read-done s=0)
        finish_tile(j0);
        step(0, 2, 4, -1, 0);     // s=2: gate B2 (B3 in flight)
        step(1, 0, 0, -1, 0);     // s=3: gate B3 (drain: last loads)
        finish_tile(j0 + 1);
    } else {
        step(0, 0, 4, -1, 0);     // s=0: gate B0 (B1's 4 loads stay in flight)
        step(1, 1, 0, -1, 0);     // s=1: drain B1
        finish_tile(j0);
    }

    // --- block reduction -> one partial per block, no atomics ---
#pragma unroll
    for (int off = 32; off >= 1; off >>= 1) local += __shfl_down(local, off);
    if (l == 0) red[w] = local;
    __syncthreads();
    if (t == 0) part[orig] = red[0] + red[1] + red[2] + red[3];
}

// --- Kernel 3: reduce NBLOCKS=1056 partials, finalize ---
__global__ __launch_bounds__(256) void fin_kernel(const float* __restrict__ part,
                                                  float* __restrict__ out) {
    __shared__ float red[4];
    const int t = threadIdx.x;
    float v = part[t] + part[t + 256] + part[t + 512] + part[t + 768]
            + (t < NBLOCKS - 1024 ? part[t + 1024] : 0.0f);
#pragma unroll
    for (int off = 32; off >= 1; off >>= 1) v += __shfl_down(v, off);
    if ((t & 63) == 0) red[t >> 6] = v;
    __syncthreads();
    if (t == 0) out[0] = (red[0] + red[1] + red[2] + red[3]) / 33550336.0f;
}

extern "C" void kernel_launch(void* const* d_in, const int* in_sizes, int n_in,
                              void* d_out, int out_size, void* d_ws, size_t ws_size,
                              hipStream_t stream) {
    const float* x = (const float*)d_in[0];
    float* out = (float*)d_out;
    unsigned char* e = (unsigned char*)d_ws;                        // 2 MB fp8
    float* part = (float*)((char*)d_ws + (size_t)NROWS * DCOLS);    // 1056 floats

    norm_kernel<<<NROWS / 8, 256, 0, stream>>>(x, e);
    tile_kernel<<<NBLOCKS, 256, 0, stream>>>(e, part);
    fin_kernel<<<1, 256, 0, stream>>>(part, out);
}

// Round 24
// 37.277 us; speedup vs baseline: 1.1170x; 1.0277x over previous
//
#include <hip/hip_runtime.h>
#include <hip/hip_fp16.h>

typedef __attribute__((ext_vector_type(4))) float f32x4;
typedef __attribute__((ext_vector_type(8))) int i32x8;

#define NROWS 8192
#define DCOLS 256
#define MARGIN 0.5f
#define NT 64          // 8192/128 tiles per dim
#define NBLOCKS 544    // sum over rows bi of ceil((64-bi)/4), runs of <=4

// --- Kernel 1: L2-normalize rows fp32 -> fp8 e5m2 (= truncated fp16), row-major.
__global__ __launch_bounds__(256) void norm_kernel(const float* __restrict__ x,
                                                   unsigned char* __restrict__ e) {
    const int t = threadIdx.x;
    const int l = t & 63;
    const int c = l & 31;
    const int row = blockIdx.x * 8 + (t >> 6) * 2 + (l >> 5);

    const float4 v0 = *reinterpret_cast<const float4*>(&x[row * DCOLS + c * 8]);
    const float4 v1 = *reinterpret_cast<const float4*>(&x[row * DCOLS + c * 8 + 4]);
    float ss = v0.x * v0.x + v0.y * v0.y + v0.z * v0.z + v0.w * v0.w
             + v1.x * v1.x + v1.y * v1.y + v1.z * v1.z + v1.w * v1.w;
#pragma unroll
    for (int off = 16; off >= 1; off >>= 1) ss += __shfl_xor(ss, off, 32);
    const float inv = 1.0f / fmaxf(sqrtf(ss), 1e-12f);

    const float f[8] = {v0.x, v0.y, v0.z, v0.w, v1.x, v1.y, v1.z, v1.w};
    unsigned int lo = 0, hi = 0;
#pragma unroll
    for (int i = 0; i < 4; ++i) {
        const unsigned short hb = __half_as_ushort(__float2half(f[i] * inv));
        lo |= (unsigned int)(hb >> 8) << (8 * i);           // e5m2 = fp16 top byte
    }
#pragma unroll
    for (int i = 0; i < 4; ++i) {
        const unsigned short hb = __half_as_ushort(__float2half(f[4 + i] * inv));
        hi |= (unsigned int)(hb >> 8) << (8 * i);
    }
    uint2 o; o.x = lo; o.y = hi;
    *reinterpret_cast<uint2*>(e + (size_t)row * DCOLS + c * 8) = o;
}

// --- Kernel 2: R24 = R18 champion (30.8us) + single-round prologue graft.
// Block = (bi, run of <=4 j-tiles), 256 thr = 4 free waves. Tile 128x128;
// wave owns cols wn*32 -> acc[8][2] of mfma_scale_f32_16x16x128 (bf8/bf8,
// scale=1.0, verified in-context R18). A (128 x K=256 fp8) staged in ONE
// 32KB round, ONE barrier, no vmcnt(0) drain; hoisted to af[2][8] regs.
// B: wave-private 4KB ring-3, own-vmcnt counted gates (vmcnt(4); final step
// vmcnt(0) to close R18's theoretical under-wait), no in-loop barriers.
// LDS 80KB -> 2 blocks/CU.
__global__ __launch_bounds__(256, 2) void tile_kernel(const unsigned char* __restrict__ e,
                                                      float* __restrict__ part) {
    // XCD-chunked bijective remap (544 = 8*68)
    const int orig = blockIdx.x;
    int bb = (orig & 7) * 68 + (orig >> 3);
    int bi = 0;
    while (bb >= ((NT - bi) + 3) >> 2) { bb -= ((NT - bi) + 3) >> 2; ++bi; }
    const int j0 = bi + bb * 4;
    const int nj = min(4, NT - j0);
    const int NS = nj * 2;                    // (tile, kb) streams

    __shared__ char As[32768];                // [kb 0..1][hk 0..3][row 0..127][32B]
    __shared__ char Bw[4][3][4096];           // [wave][slot][hk 0..3][brow 0..31][32B]
    __shared__ float red[4];

    const int t = threadIdx.x;
    const int l = t & 63;
    const int w = t >> 6;       // wave id: cols wn*32
    const int wn = w;
    const int lr = l & 15;
    const int hk = l >> 4;
    const unsigned char* eA = e + (size_t)bi * 128 * DCOLS;
    char* myB = Bw[w][0];

    // stage one B stream (tile j0+(s>>1), kb = s&1): 4KB, 4 loads/lane.
    auto stageB = [&](int s, int slot) {
        const int jt = j0 + (s >> 1), kb = s & 1;
        const unsigned char* src = e + (size_t)(jt * 128 + wn * 32) * DCOLS + kb * 128;
#pragma unroll
        for (int i = 0; i < 4; ++i) {
            const int u = i * 64 + l;         // 0..255
            const int hk2 = u >> 6, brow = (u >> 1) & 31, half = u & 1;
            __builtin_amdgcn_global_load_lds(
                (const __attribute__((address_space(1))) void*)(src + brow * DCOLS + hk2 * 32 + half * 16),
                (__attribute__((address_space(3))) void*)(myB + slot * 4096 + u * 16), 16, 0, 0);
        }
    };

    // --- prologue (single round): A 32KB (8 loads/thread) + B streams 0,1 ---
#pragma unroll
    for (int i = 0; i < 8; ++i) {
        const int u = i * 256 + t;            // 0..2047
        const int kb = u >> 10, hk2 = (u >> 8) & 3, arow = (u >> 1) & 127, half = u & 1;
        __builtin_amdgcn_global_load_lds(
            (const __attribute__((address_space(1))) void*)(eA + arow * DCOLS + kb * 128 + hk2 * 32 + half * 16),
            (__attribute__((address_space(3))) void*)(As + u * 16), 16, 0, 0);
    }
    stageB(0, 0);                             // stream 0 = (j0, kb0)
    stageB(1, 1);                             // stream 1 = (j0, kb1) — always exists
    asm volatile("s_waitcnt vmcnt(8)" ::: "memory");   // 16 outstanding -> A landed
    __builtin_amdgcn_s_barrier();             // the ONLY barrier: publishes A
    __builtin_amdgcn_sched_barrier(0);

    // --- hoist ALL A fragments to registers (one pass; As then dead) ---
    i32x8 af[2][8];
#pragma unroll
    for (int kb = 0; kb < 2; ++kb)
#pragma unroll
        for (int m = 0; m < 8; ++m)
            af[kb][m] = *reinterpret_cast<const i32x8*>(
                As + kb * 16384 + hk * 4096 + (m * 16 + lr) * 32);

    f32x4 acc[8][2];
#pragma unroll
    for (int m = 0; m < 8; ++m)
#pragma unroll
        for (int n = 0; n < 2; ++n)
            acc[m][n] = (f32x4){0.f, 0.f, 0.f, 0.f};

    float local = 0.0f;
    for (int jx = 0; jx < nj; ++jx) {
        const int jt = j0 + jx;
#pragma unroll
        for (int kb = 0; kb < 2; ++kb) {
            const int s = jx * 2 + kb;
            // gate: own stream s landed. Steady state: B_s + B_{s+1} in flight
            // -> vmcnt(4) retires B_s. Final step: only B_s in flight -> drain.
            if (s == NS - 1) asm volatile("s_waitcnt vmcnt(0)" ::: "memory");
            else             asm volatile("s_waitcnt vmcnt(4)" ::: "memory");
            // stage stream s+2 into slot (s+2)%3 = slot last read at step s-1
            // (those ds_reads were consumed by step s-1's MFMAs -> in-order safe)
            if (s + 2 < NS) {
                int sl2 = s + 2; while (sl2 >= 3) sl2 -= 3;
                stageB(s + 2, sl2);
            }
            int slc = s; while (slc >= 3) slc -= 3;
            i32x8 bf[2];
#pragma unroll
            for (int n = 0; n < 2; ++n)
                bf[n] = *reinterpret_cast<const i32x8*>(
                    myB + slc * 4096 + hk * 1024 + (n * 16 + lr) * 32);
            __builtin_amdgcn_s_setprio(1);
#pragma unroll
            for (int m = 0; m < 8; ++m)
#pragma unroll
                for (int n = 0; n < 2; ++n)
                    acc[m][n] = __builtin_amdgcn_mfma_scale_f32_16x16x128_f8f6f4(
                        af[kb][m], bf[n], acc[m][n],
                        1, 1,                 // cbsz=BF8(e5m2), blgp=BF8
                        0, 0x7F7F7F7F,        // scale A = 1.0
                        0, 0x7F7F7F7F);       // scale B = 1.0
            __builtin_amdgcn_s_setprio(0);
        }
        // --- tile jt complete: fused masked-relu reduce, reset acc ---
        // C/D layout (m89-verified; shape-determined): col=lane&15,
        // row=(lane>>4)*4+reg.
        const int gi0 = bi * 128;
        const int gj0 = jt * 128 + wn * 32;
        if (jt == bi) {
#pragma unroll
            for (int m = 0; m < 8; ++m)
#pragma unroll
                for (int n = 0; n < 2; ++n) {
#pragma unroll
                    for (int r2 = 0; r2 < 4; ++r2) {
                        const int gi = gi0 + m * 16 + hk * 4 + r2;
                        const int gj = gj0 + n * 16 + lr;
                        local += (gi < gj) ? fmaxf(acc[m][n][r2] - MARGIN, 0.0f) : 0.0f;
                    }
                    acc[m][n] = (f32x4){0.f, 0.f, 0.f, 0.f};
                }
        } else {   // jt > bi: all pairs strictly upper-triangular
#pragma unroll
            for (int m = 0; m < 8; ++m)
#pragma unroll
                for (int n = 0; n < 2; ++n) {
#pragma unroll
                    for (int r2 = 0; r2 < 4; ++r2)
                        local += fmaxf(acc[m][n][r2] - MARGIN, 0.0f);
                    acc[m][n] = (f32x4){0.f, 0.f, 0.f, 0.f};
                }
        }
    }

    // --- block reduction -> one partial per block, no atomics ---
#pragma unroll
    for (int off = 32; off >= 1; off >>= 1) local += __shfl_down(local, off);
    if (l == 0) red[w] = local;
    __syncthreads();
    if (t == 0) part[orig] = red[0] + red[1] + red[2] + red[3];
}

// --- Kernel 3: reduce NBLOCKS=544 partials, finalize ---
__global__ __launch_bounds__(256) void fin_kernel(const float* __restrict__ part,
                                                  float* __restrict__ out) {
    __shared__ float red[4];
    const int t = threadIdx.x;
    float v = part[t] + part[t + 256] + (t < NBLOCKS - 512 ? part[t + 512] : 0.0f);
#pragma unroll
    for (int off = 32; off >= 1; off >>= 1) v += __shfl_down(v, off);
    if ((t & 63) == 0) red[t >> 6] = v;
    __syncthreads();
    if (t == 0) out[0] = (red[0] + red[1] + red[2] + red[3]) / 33550336.0f;
}

extern "C" void kernel_launch(void* const* d_in, const int* in_sizes, int n_in,
                              void* d_out, int out_size, void* d_ws, size_t ws_size,
                              hipStream_t stream) {
    const float* x = (const float*)d_in[0];
    float* out = (float*)d_out;
    unsigned char* e = (unsigned char*)d_ws;                        // 2 MB fp8
    float* part = (float*)((char*)d_ws + (size_t)NROWS * DCOLS);    // 544 floats

    norm_kernel<<<NROWS / 8, 256, 0, stream>>>(x, e);
    tile_kernel<<<NBLOCKS, 256, 0, stream>>>(e, part);
    fin_kernel<<<1, 256, 0, stream>>>(part, out);
}

// Round 25
// 30.654 us; speedup vs baseline: 1.3583x; 1.2160x over previous
//
#include <hip/hip_runtime.h>
#include <hip/hip_fp16.h>

typedef __attribute__((ext_vector_type(4))) float f32x4;
typedef __attribute__((ext_vector_type(8))) int i32x8;

#define NROWS 8192
#define DCOLS 256
#define MARGIN 0.5f
#define NT 64          // 8192/128 tiles per dim
#define NBLOCKS 544    // sum over rows bi of ceil((64-bi)/4) runs of <=4 j-tiles

// --- Kernel 1: L2-normalize rows fp32 -> fp8 e5m2 (= truncated fp16), row-major.
__global__ __launch_bounds__(256) void norm_kernel(const float* __restrict__ x,
                                                   unsigned char* __restrict__ e) {
    const int t = threadIdx.x;
    const int l = t & 63;
    const int c = l & 31;
    const int row = blockIdx.x * 8 + (t >> 6) * 2 + (l >> 5);

    const float4 v0 = *reinterpret_cast<const float4*>(&x[row * DCOLS + c * 8]);
    const float4 v1 = *reinterpret_cast<const float4*>(&x[row * DCOLS + c * 8 + 4]);
    float ss = v0.x * v0.x + v0.y * v0.y + v0.z * v0.z + v0.w * v0.w
             + v1.x * v1.x + v1.y * v1.y + v1.z * v1.z + v1.w * v1.w;
#pragma unroll
    for (int off = 16; off >= 1; off >>= 1) ss += __shfl_xor(ss, off, 32);
    const float inv = 1.0f / fmaxf(sqrtf(ss), 1e-12f);

    const float f[8] = {v0.x, v0.y, v0.z, v0.w, v1.x, v1.y, v1.z, v1.w};
    unsigned int lo = 0, hi = 0;
#pragma unroll
    for (int i = 0; i < 4; ++i) {
        const unsigned short hb = __half_as_ushort(__float2half(f[i] * inv));
        lo |= (unsigned int)(hb >> 8) << (8 * i);           // e5m2 = fp16 top byte
    }
#pragma unroll
    for (int i = 0; i < 4; ++i) {
        const unsigned short hb = __half_as_ushort(__float2half(f[4 + i] * inv));
        hi |= (unsigned int)(hb >> 8) << (8 * i);
    }
    uint2 o; o.x = lo; o.y = hi;
    *reinterpret_cast<uint2*>(e + (size_t)row * DCOLS + c * 8) = o;
}

// --- Kernel 2 (R18 champion, 30.8us — final): MX-fp8 K=128 MFMA +
// A-in-registers + barrier-free wave-private B pipeline. Block = (bi, run of
// <=4 j-tiles), 256 thr = 4 free waves. Tile 128x128; wave owns cols wn*32:
// acc[8][2] of mfma_scale_f32_16x16x128 (bf8/bf8, scale=1.0). K=256 -> 2
// K128-steps/tile. A panel hoisted to af[2][8] regs (128 VGPR) via a 16KB
// LDS bounce (2 rounds) -> in-loop LDS reads are B-only. B: wave-private
// 4KB ring-3, own-vmcnt counted gating (vmcnt(4)), no in-loop barriers.
__global__ __launch_bounds__(256, 2) void tile_kernel(const unsigned char* __restrict__ e,
                                                      float* __restrict__ part) {
    // XCD-chunked bijective remap (544 = 8*68)
    const int orig = blockIdx.x;
    int bb = (orig & 7) * 68 + (orig >> 3);
    int bi = 0;
    while (bb >= ((NT - bi) + 3) >> 2) { bb -= ((NT - bi) + 3) >> 2; ++bi; }
    const int j0 = bi + bb * 4;
    const int nj = min(4, NT - j0);
    const int NS = nj * 2;                    // K128-steps

    __shared__ char lds[65536];               // [0,16K): A bounce ; [16K,64K): Bw
    char* As = lds;                           // 16KB: [hk][row128][32B]
    char* Bw = lds + 16384;                   // 4 waves x 3 slots x 4KB
    float* red = (float*)lds;                 // reuse dead A region at the end

    const int t = threadIdx.x;
    const int l = t & 63;
    const int w = t >> 6;       // wave id = N-slice: cols wn*32
    const int wn = w;
    const int lr = l & 15;
    const int hk = l >> 4;
    const unsigned char* eA = e + (size_t)bi * 128 * DCOLS;
    const unsigned char* eB = e + (size_t)j0 * 128 * DCOLS + wn * 32 * DCOLS;
    char* myB = Bw + w * 12288;

    // stage one B K128-panel (stream s: tile j0+(s>>1), kblock s&1) into a slot.
    auto stageB = [&](int stream, int slot) {
#pragma unroll
        for (int i = 0; i < 4; ++i) {
            const int u = i * 64 + l;
            const int shk = (u >> 6) & 3, srow = (u >> 1) & 31, sc = u & 1;
            __builtin_amdgcn_global_load_lds(
                (const __attribute__((address_space(1))) void*)(eB
                    + (size_t)(stream >> 1) * 128 * DCOLS
                    + srow * DCOLS + (stream & 1) * 128 + shk * 32 + sc * 16),
                (__attribute__((address_space(3))) void*)(myB + slot * 4096 + u * 16),
                16, 0, 0);
        }
    };

    // --- prologue ---
    // A round 0 (kblock 0): 4 loads/thread.
#pragma unroll
    for (int i = 0; i < 4; ++i) {
        const int u = i * 256 + t;
        const int shk = (u >> 8) & 3, srow = (u >> 1) & 127, sc = u & 1;
        __builtin_amdgcn_global_load_lds(
            (const __attribute__((address_space(1))) void*)(eA + srow * DCOLS + shk * 32 + sc * 16),
            (__attribute__((address_space(3))) void*)(As + u * 16), 16, 0, 0);
    }
    stageB(0, 0);
    stageB(1, 1);
    asm volatile("s_waitcnt vmcnt(8)" ::: "memory");   // A0 landed; 8 B in flight
    __builtin_amdgcn_s_barrier();
    __builtin_amdgcn_sched_barrier(0);

    i32x8 af[2][8];
#pragma unroll
    for (int m = 0; m < 8; ++m)
        af[0][m] = *reinterpret_cast<const i32x8*>(As + hk * 4096 + (m * 16 + lr) * 32);
    __builtin_amdgcn_s_barrier();             // all waves done reading A0
    __builtin_amdgcn_sched_barrier(0);
    // A round 1 (kblock 1) into the same 16KB
#pragma unroll
    for (int i = 0; i < 4; ++i) {
        const int u = i * 256 + t;
        const int shk = (u >> 8) & 3, srow = (u >> 1) & 127, sc = u & 1;
        __builtin_amdgcn_global_load_lds(
            (const __attribute__((address_space(1))) void*)(eA + srow * DCOLS + 128 + shk * 32 + sc * 16),
            (__attribute__((address_space(3))) void*)(As + u * 16), 16, 0, 0);
    }
    asm volatile("s_waitcnt vmcnt(0)" ::: "memory");   // drain (prologue-only)
    __builtin_amdgcn_s_barrier();
    __builtin_amdgcn_sched_barrier(0);
#pragma unroll
    for (int m = 0; m < 8; ++m)
        af[1][m] = *reinterpret_cast<const i32x8*>(As + hk * 4096 + (m * 16 + lr) * 32);
    // As now dead (red[] reuses it after the loop). B streams 0,1 landed.

    f32x4 acc[8][2];
#pragma unroll
    for (int m = 0; m < 8; ++m)
#pragma unroll
        for (int n = 0; n < 2; ++n)
            acc[m][n] = (f32x4){0.f, 0.f, 0.f, 0.f};

    float local = 0.0f;
    for (int jx = 0; jx < nj; ++jx) {
        const int jt = j0 + jx;
#pragma unroll
        for (int kb = 0; kb < 2; ++kb) {
            const int s = jx * 2 + kb;
            // own oldest B stage has landed (counted; trivially true for s<2)
            asm volatile("s_waitcnt vmcnt(4)" ::: "memory");
            // stage stream s+2 into slot (s+2)%3 (wrap: identical bytes, benign)
            {
                int s2 = s + 2; if (s2 >= NS) s2 -= NS;
                int slot = s + 2; while (slot >= 3) slot -= 3;
                stageB(s2, slot);
            }
            int slotc = s; while (slotc >= 3) slotc -= 3;
            i32x8 bf[2];
#pragma unroll
            for (int n = 0; n < 2; ++n)
                bf[n] = *reinterpret_cast<const i32x8*>(
                    myB + slotc * 4096 + hk * 1024 + (n * 16 + lr) * 32);
            __builtin_amdgcn_s_setprio(1);
#pragma unroll
            for (int m = 0; m < 8; ++m)
#pragma unroll
                for (int n = 0; n < 2; ++n)
                    acc[m][n] = __builtin_amdgcn_mfma_scale_f32_16x16x128_f8f6f4(
                        af[kb][m], bf[n], acc[m][n],
                        1, 1,                     // cbsz=BF8(e5m2), blgp=BF8
                        0, 0x7F7F7F7F,            // scale A = 1.0
                        0, 0x7F7F7F7F);           // scale B = 1.0
            __builtin_amdgcn_s_setprio(0);
        }
        // --- tile jt complete: fused masked-relu reduce, reset acc ---
        // C/D layout (m89-verified; shape-determined for f8f6f4): col=lane&15,
        // row=(lane>>4)*4+reg.
        const int gi0 = bi * 128;
        const int gj0 = jt * 128 + wn * 32;
        if (jt == bi) {
#pragma unroll
            for (int m = 0; m < 8; ++m)
#pragma unroll
                for (int n = 0; n < 2; ++n) {
#pragma unroll
                    for (int r = 0; r < 4; ++r) {
                        const int gi = gi0 + m * 16 + hk * 4 + r;
                        const int gj = gj0 + n * 16 + lr;
                        local += (gi < gj) ? fmaxf(acc[m][n][r] - MARGIN, 0.0f) : 0.0f;
                    }
                    acc[m][n] = (f32x4){0.f, 0.f, 0.f, 0.f};
                }
        } else {   // jt > bi: all pairs strictly upper-triangular
#pragma unroll
            for (int m = 0; m < 8; ++m)
#pragma unroll
                for (int n = 0; n < 2; ++n) {
#pragma unroll
                    for (int r = 0; r < 4; ++r)
                        local += fmaxf(acc[m][n][r] - MARGIN, 0.0f);
                    acc[m][n] = (f32x4){0.f, 0.f, 0.f, 0.f};
                }
        }
    }

    // --- block reduction -> one partial per block, no atomics ---
#pragma unroll
    for (int off = 32; off >= 1; off >>= 1) local += __shfl_down(local, off);
    __syncthreads();                          // all loop-LDS traffic done
    if (l == 0) red[w] = local;
    __syncthreads();
    if (t == 0) part[orig] = red[0] + red[1] + red[2] + red[3];
}

// --- Kernel 3: reduce NBLOCKS partials, finalize ---
__global__ __launch_bounds__(256) void fin_kernel(const float* __restrict__ part,
                                                  float* __restrict__ out) {
    __shared__ float red[4];
    const int t = threadIdx.x;
    float v = part[t] + part[t + 256] + (t < NBLOCKS - 512 ? part[t + 512] : 0.0f);
#pragma unroll
    for (int off = 32; off >= 1; off >>= 1) v += __shfl_down(v, off);
    if ((t & 63) == 0) red[t >> 6] = v;
    __syncthreads();
    if (t == 0) out[0] = (red[0] + red[1] + red[2] + red[3]) / 33550336.0f;
}

extern "C" void kernel_launch(void* const* d_in, const int* in_sizes, int n_in,
                              void* d_out, int out_size, void* d_ws, size_t ws_size,
                              hipStream_t stream) {
    const float* x = (const float*)d_in[0];
    float* out = (float*)d_out;
    unsigned char* e = (unsigned char*)d_ws;                        // 2 MB fp8
    float* part = (float*)((char*)d_ws + (size_t)NROWS * DCOLS);    // 544 floats

    norm_kernel<<<NROWS / 8, 256, 0, stream>>>(x, e);
    tile_kernel<<<NBLOCKS, 256, 0, stream>>>(e, part);
    fin_kernel<<<1, 256, 0, stream>>>(part, out);
}

// Round 26
// 27.798 us; speedup vs baseline: 1.4979x; 1.1028x over previous
//
#include <hip/hip_runtime.h>
#include <hip/hip_fp16.h>

typedef __attribute__((ext_vector_type(4))) float f32x4;
typedef __attribute__((ext_vector_type(8))) int i32x8;

#define NROWS 8192
#define DCOLS 256
#define MARGIN 0.5f
#define NT 64          // 8192/128 tiles per dim
#define NBLOCKS 442    // sum over rows bi of ceil((64-bi)/5), runs of <=5

// --- Kernel 1: L2-normalize rows fp32 -> fp8 e5m2 (= truncated fp16), row-major.
__global__ __launch_bounds__(256) void norm_kernel(const float* __restrict__ x,
                                                   unsigned char* __restrict__ e) {
    const int t = threadIdx.x;
    const int l = t & 63;
    const int c = l & 31;
    const int row = blockIdx.x * 8 + (t >> 6) * 2 + (l >> 5);

    const float4 v0 = *reinterpret_cast<const float4*>(&x[row * DCOLS + c * 8]);
    const float4 v1 = *reinterpret_cast<const float4*>(&x[row * DCOLS + c * 8 + 4]);
    float ss = v0.x * v0.x + v0.y * v0.y + v0.z * v0.z + v0.w * v0.w
             + v1.x * v1.x + v1.y * v1.y + v1.z * v1.z + v1.w * v1.w;
#pragma unroll
    for (int off = 16; off >= 1; off >>= 1) ss += __shfl_xor(ss, off, 32);
    const float inv = 1.0f / fmaxf(sqrtf(ss), 1e-12f);

    const float f[8] = {v0.x, v0.y, v0.z, v0.w, v1.x, v1.y, v1.z, v1.w};
    unsigned int lo = 0, hi = 0;
#pragma unroll
    for (int i = 0; i < 4; ++i) {
        const unsigned short hb = __half_as_ushort(__float2half(f[i] * inv));
        lo |= (unsigned int)(hb >> 8) << (8 * i);           // e5m2 = fp16 top byte
    }
#pragma unroll
    for (int i = 0; i < 4; ++i) {
        const unsigned short hb = __half_as_ushort(__float2half(f[4 + i] * inv));
        hi |= (unsigned int)(hb >> 8) << (8 * i);
    }
    uint2 o; o.x = lo; o.y = hi;
    *reinterpret_cast<uint2*>(e + (size_t)row * DCOLS + c * 8) = o;
}

// --- Kernel 2: R26 = R18 champion with runs of <=5 (442 blocks <= 512
// co-residency slots -> SINGLE generation, no serial tail; A amortized over 5
// tiles). Pipeline byte-identical to R18: 256 thr = 4 free waves, tile
// 128x128, wave owns cols wn*32 -> acc[8][2] of mfma_scale_f32_16x16x128
// (bf8/bf8, scale=1.0, verified in-context R18). A hoisted to af[2][8] regs
// via 16KB LDS bounce (2 rounds); B wave-private 4KB ring-3, own-vmcnt
// counted gating (vmcnt(4)), no in-loop barriers. LDS 64KB -> 2 blocks/CU.
__global__ __launch_bounds__(256, 2) void tile_kernel(const unsigned char* __restrict__ e,
                                                      float* __restrict__ part) {
    // bijective XCD remap for 442 = 8*55 + 2 (m204 q/r formula, ERRATA #11)
    const int orig = blockIdx.x;
    const int xcd = orig & 7, idx = orig >> 3;
    int bb = (xcd < 2 ? xcd * 56 : 2 * 56 + (xcd - 2) * 55) + idx;
    int bi = 0, r;
    while (bb >= (r = ((NT - bi) + 4) / 5)) { bb -= r; ++bi; }
    const int j0 = bi + bb * 5;
    const int nj = min(5, NT - j0);
    const int NS = nj * 2;                    // K128-steps (<=10)

    __shared__ char lds[65536];               // [0,16K): A bounce ; [16K,64K): Bw
    char* As = lds;                           // 16KB: [hk][row128][32B]
    char* Bw = lds + 16384;                   // 4 waves x 3 slots x 4KB
    float* red = (float*)lds;                 // reuse dead A region at the end

    const int t = threadIdx.x;
    const int l = t & 63;
    const int w = t >> 6;       // wave id = N-slice: cols wn*32
    const int wn = w;
    const int lr = l & 15;
    const int hk = l >> 4;
    const unsigned char* eA = e + (size_t)bi * 128 * DCOLS;
    const unsigned char* eB = e + (size_t)j0 * 128 * DCOLS + wn * 32 * DCOLS;
    char* myB = Bw + w * 12288;

    // stage one B K128-panel (stream s: tile j0+(s>>1), kblock s&1) into a slot.
    auto stageB = [&](int stream, int slot) {
#pragma unroll
        for (int i = 0; i < 4; ++i) {
            const int u = i * 64 + l;
            const int shk = (u >> 6) & 3, srow = (u >> 1) & 31, sc = u & 1;
            __builtin_amdgcn_global_load_lds(
                (const __attribute__((address_space(1))) void*)(eB
                    + (size_t)(stream >> 1) * 128 * DCOLS
                    + srow * DCOLS + (stream & 1) * 128 + shk * 32 + sc * 16),
                (__attribute__((address_space(3))) void*)(myB + slot * 4096 + u * 16),
                16, 0, 0);
        }
    };

    // --- prologue ---
    // A round 0 (kblock 0): 4 loads/thread.
#pragma unroll
    for (int i = 0; i < 4; ++i) {
        const int u = i * 256 + t;
        const int shk = (u >> 8) & 3, srow = (u >> 1) & 127, sc = u & 1;
        __builtin_amdgcn_global_load_lds(
            (const __attribute__((address_space(1))) void*)(eA + srow * DCOLS + shk * 32 + sc * 16),
            (__attribute__((address_space(3))) void*)(As + u * 16), 16, 0, 0);
    }
    stageB(0, 0);
    stageB(1, 1);
    asm volatile("s_waitcnt vmcnt(8)" ::: "memory");   // A0 landed; 8 B in flight
    __builtin_amdgcn_s_barrier();
    __builtin_amdgcn_sched_barrier(0);

    i32x8 af[2][8];
#pragma unroll
    for (int m = 0; m < 8; ++m)
        af[0][m] = *reinterpret_cast<const i32x8*>(As + hk * 4096 + (m * 16 + lr) * 32);
    __builtin_amdgcn_s_barrier();             // all waves done reading A0
    __builtin_amdgcn_sched_barrier(0);
    // A round 1 (kblock 1) into the same 16KB
#pragma unroll
    for (int i = 0; i < 4; ++i) {
        const int u = i * 256 + t;
        const int shk = (u >> 8) & 3, srow = (u >> 1) & 127, sc = u & 1;
        __builtin_amdgcn_global_load_lds(
            (const __attribute__((address_space(1))) void*)(eA + srow * DCOLS + 128 + shk * 32 + sc * 16),
            (__attribute__((address_space(3))) void*)(As + u * 16), 16, 0, 0);
    }
    asm volatile("s_waitcnt vmcnt(0)" ::: "memory");   // drain (prologue-only)
    __builtin_amdgcn_s_barrier();
    __builtin_amdgcn_sched_barrier(0);
#pragma unroll
    for (int m = 0; m < 8; ++m)
        af[1][m] = *reinterpret_cast<const i32x8*>(As + hk * 4096 + (m * 16 + lr) * 32);
    // As now dead (red[] reuses it after the loop). B streams 0,1 landed.

    f32x4 acc[8][2];
#pragma unroll
    for (int m = 0; m < 8; ++m)
#pragma unroll
        for (int n = 0; n < 2; ++n)
            acc[m][n] = (f32x4){0.f, 0.f, 0.f, 0.f};

    float local = 0.0f;
    for (int jx = 0; jx < nj; ++jx) {
        const int jt = j0 + jx;
#pragma unroll
        for (int kb = 0; kb < 2; ++kb) {
            const int s = jx * 2 + kb;
            // own oldest B stage has landed (counted; trivially true for s<2)
            asm volatile("s_waitcnt vmcnt(4)" ::: "memory");
            // stage stream s+2 into slot (s+2)%3 (wrap: identical bytes, benign)
            {
                int s2 = s + 2; if (s2 >= NS) s2 -= NS;
                int slot = s + 2; while (slot >= 3) slot -= 3;
                stageB(s2, slot);
            }
            int slotc = s; while (slotc >= 3) slotc -= 3;
            i32x8 bf[2];
#pragma unroll
            for (int n = 0; n < 2; ++n)
                bf[n] = *reinterpret_cast<const i32x8*>(
                    myB + slotc * 4096 + hk * 1024 + (n * 16 + lr) * 32);
            __builtin_amdgcn_s_setprio(1);
#pragma unroll
            for (int m = 0; m < 8; ++m)
#pragma unroll
                for (int n = 0; n < 2; ++n)
                    acc[m][n] = __builtin_amdgcn_mfma_scale_f32_16x16x128_f8f6f4(
                        af[kb][m], bf[n], acc[m][n],
                        1, 1,                     // cbsz=BF8(e5m2), blgp=BF8
                        0, 0x7F7F7F7F,            // scale A = 1.0
                        0, 0x7F7F7F7F);           // scale B = 1.0
            __builtin_amdgcn_s_setprio(0);
        }
        // --- tile jt complete: fused masked-relu reduce, reset acc ---
        // C/D layout (m89-verified; shape-determined for f8f6f4): col=lane&15,
        // row=(lane>>4)*4+reg.
        const int gi0 = bi * 128;
        const int gj0 = jt * 128 + wn * 32;
        if (jt == bi) {
#pragma unroll
            for (int m = 0; m < 8; ++m)
#pragma unroll
                for (int n = 0; n < 2; ++n) {
#pragma unroll
                    for (int r2 = 0; r2 < 4; ++r2) {
                        const int gi = gi0 + m * 16 + hk * 4 + r2;
                        const int gj = gj0 + n * 16 + lr;
                        local += (gi < gj) ? fmaxf(acc[m][n][r2] - MARGIN, 0.0f) : 0.0f;
                    }
                    acc[m][n] = (f32x4){0.f, 0.f, 0.f, 0.f};
                }
        } else {   // jt > bi: all pairs strictly upper-triangular
#pragma unroll
            for (int m = 0; m < 8; ++m)
#pragma unroll
                for (int n = 0; n < 2; ++n) {
#pragma unroll
                    for (int r2 = 0; r2 < 4; ++r2)
                        local += fmaxf(acc[m][n][r2] - MARGIN, 0.0f);
                    acc[m][n] = (f32x4){0.f, 0.f, 0.f, 0.f};
                }
        }
    }

    // --- block reduction -> one partial per block, no atomics ---
#pragma unroll
    for (int off = 32; off >= 1; off >>= 1) local += __shfl_down(local, off);
    __syncthreads();                          // all loop-LDS traffic done
    if (l == 0) red[w] = local;
    __syncthreads();
    if (t == 0) part[orig] = red[0] + red[1] + red[2] + red[3];
}

// --- Kernel 3: reduce NBLOCKS=442 partials, finalize ---
__global__ __launch_bounds__(256) void fin_kernel(const float* __restrict__ part,
                                                  float* __restrict__ out) {
    __shared__ float red[4];
    const int t = threadIdx.x;
    float v = part[t] + (t < NBLOCKS - 256 ? part[t + 256] : 0.0f);
#pragma unroll
    for (int off = 32; off >= 1; off >>= 1) v += __shfl_down(v, off);
    if ((t & 63) == 0) red[t >> 6] = v;
    __syncthreads();
    if (t == 0) out[0] = (red[0] + red[1] + red[2] + red[3]) / 33550336.0f;
}

extern "C" void kernel_launch(void* const* d_in, const int* in_sizes, int n_in,
                              void* d_out, int out_size, void* d_ws, size_t ws_size,
                              hipStream_t stream) {
    const float* x = (const float*)d_in[0];
    float* out = (float*)d_out;
    unsigned char* e = (unsigned char*)d_ws;                        // 2 MB fp8
    float* part = (float*)((char*)d_ws + (size_t)NROWS * DCOLS);    // 442 floats

    norm_kernel<<<NROWS / 8, 256, 0, stream>>>(x, e);
    tile_kernel<<<NBLOCKS, 256, 0, stream>>>(e, part);
    fin_kernel<<<1, 256, 0, stream>>>(part, out);
}